// Round 19
// baseline (1050.065 us; speedup 1.0000x reference)
//
#include <hip/hip_runtime.h>
#include <hip/hip_bf16.h>
#include <math.h>

using bf16   = __hip_bfloat16;
using f32x4  = __attribute__((ext_vector_type(4))) float;
using bf16x8 = __attribute__((ext_vector_type(8))) short;
using s16x4  = __attribute__((ext_vector_type(4))) short;

constexpr int SEQ    = 2048;
constexpr int DMODEL = 768;
constexpr int NHEAD  = 12;
constexpr int NV     = 50257;
constexpr int NVPAD  = 50304;
constexpr int NB     = NVPAD / 128;   // 393 column panels
constexpr int NLAYER = 4;
constexpr int KSPLIT = 3;

__device__ __forceinline__ void gload_lds16(const void* g, void* s) {
    __builtin_amdgcn_global_load_lds((const __attribute__((address_space(1))) void*)g,
                                     (__attribute__((address_space(3))) void*)s, 16, 0, 0);
}

// ---------------- embedding ----------------
__global__ __launch_bounds__(192) void embed_kernel(const int* __restrict__ idx,
                                                    const float* __restrict__ wte,
                                                    const float* __restrict__ wpe,
                                                    float* __restrict__ x) {
    int t = blockIdx.x;
    int tok = idx[t];
    const float4* a = (const float4*)(wte + (size_t)tok * DMODEL);
    const float4* b = (const float4*)(wpe + (size_t)t * DMODEL);
    float4* o = (float4*)(x + (size_t)t * DMODEL);
    int d = threadIdx.x;
    float4 u = a[d], v = b[d];
    u.x += v.x; u.y += v.y; u.z += v.z; u.w += v.w;
    o[d] = u;
}

// ---------------- layernorm: fp32 in, bf16 out ----------------
__global__ __launch_bounds__(256) void ln_kernel(const float* __restrict__ x,
                                                 const float* __restrict__ w,
                                                 const float* __restrict__ b,
                                                 bf16* __restrict__ out) {
    __shared__ float red[8];
    int row = blockIdx.x, tid = threadIdx.x;
    const float* xr = x + (size_t)row * DMODEL;
    float v[3];
    float s = 0.f, ss = 0.f;
#pragma unroll
    for (int j = 0; j < 3; j++) {
        v[j] = xr[tid + j * 256];
        s += v[j];
        ss += v[j] * v[j];
    }
#pragma unroll
    for (int off = 32; off; off >>= 1) {
        s  += __shfl_down(s,  off, 64);
        ss += __shfl_down(ss, off, 64);
    }
    int wid = tid >> 6, lane = tid & 63;
    if (lane == 0) { red[wid] = s; red[4 + wid] = ss; }
    __syncthreads();
    s  = red[0] + red[1] + red[2] + red[3];
    ss = red[4] + red[5] + red[6] + red[7];
    float mean = s * (1.0f / DMODEL);
    float var  = ss * (1.0f / DMODEL) - mean * mean;
    float rstd = rsqrtf(var + 1e-5f);
#pragma unroll
    for (int j = 0; j < 3; j++) {
        int d = tid + j * 256;
        out[(size_t)row * DMODEL + d] = __float2bfloat16((v[j] - mean) * rstd * w[d] + b[d]);
    }
}

// ---------------- fused split-K reduce + layernorm ----------------
__global__ __launch_bounds__(192) void kredln_kernel(const float* __restrict__ partial,
                                                     const float* __restrict__ gbias,
                                                     float* __restrict__ x,
                                                     const float* __restrict__ lnw,
                                                     const float* __restrict__ lnb,
                                                     bf16* __restrict__ h) {
    __shared__ float red[6];
    int row = blockIdx.x, t = threadIdx.x;
    size_t off = (size_t)row * DMODEL + t * 4;
    f32x4 v = *(f32x4*)&x[off];
    float4 b = *(const float4*)&gbias[t * 4];
    v[0] += b.x; v[1] += b.y; v[2] += b.z; v[3] += b.w;
#pragma unroll
    for (int z = 0; z < KSPLIT; z++) {
        f32x4 p = *(const f32x4*)&partial[(size_t)z * SEQ * DMODEL + off];
        v[0] += p[0]; v[1] += p[1]; v[2] += p[2]; v[3] += p[3];
    }
    *(f32x4*)&x[off] = v;
    float s  = v[0] + v[1] + v[2] + v[3];
    float ss = v[0] * v[0] + v[1] * v[1] + v[2] * v[2] + v[3] * v[3];
#pragma unroll
    for (int o2 = 32; o2; o2 >>= 1) {
        s  += __shfl_down(s,  o2, 64);
        ss += __shfl_down(ss, o2, 64);
    }
    int wid = t >> 6, lane = t & 63;
    if (lane == 0) { red[wid] = s; red[3 + wid] = ss; }
    __syncthreads();
    s  = red[0] + red[1] + red[2];
    ss = red[3] + red[4] + red[5];
    float mean = s * (1.0f / DMODEL);
    float var  = ss * (1.0f / DMODEL) - mean * mean;
    float rstd = rsqrtf(var + 1e-5f);
    float4 w4 = *(const float4*)&lnw[t * 4];
    float4 b4 = *(const float4*)&lnb[t * 4];
    s16x4 pk;
    {
        bf16 t0 = __float2bfloat16((v[0] - mean) * rstd * w4.x + b4.x);
        bf16 t1 = __float2bfloat16((v[1] - mean) * rstd * w4.y + b4.y);
        bf16 t2 = __float2bfloat16((v[2] - mean) * rstd * w4.z + b4.z);
        bf16 t3 = __float2bfloat16((v[3] - mean) * rstd * w4.w + b4.w);
        pk[0] = *reinterpret_cast<short*>(&t0);
        pk[1] = *reinterpret_cast<short*>(&t1);
        pk[2] = *reinterpret_cast<short*>(&t2);
        pk[3] = *reinterpret_cast<short*>(&t3);
    }
    *(s16x4*)&h[off] = pk;
}

// ---------------- batched transpose + fp32->bf16: W[K][N] -> Wt[Npad][K] ----------------
__global__ __launch_bounds__(256) void transpb_kernel(const float* __restrict__ W,
                                                      bf16* __restrict__ Wt,
                                                      int K, int N,
                                                      size_t wstride, size_t tstride) {
    __shared__ float t[64][65];
    int l = blockIdx.z;
    W  += (size_t)l * wstride;
    Wt += (size_t)l * tstride;
    int n0 = blockIdx.x << 6, k0 = blockIdx.y << 6;
    int tid = threadIdx.x;
#pragma unroll
    for (int i = 0; i < 16; i++) {
        int id = tid + (i << 8);
        int r = id >> 6, c = id & 63;
        int n = n0 + c;
        t[r][c] = (n < N) ? W[(size_t)(k0 + r) * N + n] : 0.0f;
    }
    __syncthreads();
#pragma unroll
    for (int i = 0; i < 16; i++) {
        int id = tid + (i << 8);
        int nr = id >> 6, kc = id & 63;
        Wt[(size_t)(n0 + nr) * K + k0 + kc] = __float2bfloat16(t[kc][nr]);
    }
}

// ---------------- MFMA GEMM (1D grid, XCD-chunked): C = epi(A @ Wt^T) ----------------
template <int ACT, int RES, int OBF>
__global__ __launch_bounds__(256) void mgemm_kernel(const short* __restrict__ A,
                                                    const short* __restrict__ Wt,
                                                    const float* __restrict__ bias,
                                                    const float* __restrict__ res,
                                                    float* __restrict__ outf,
                                                    bf16* __restrict__ outb,
                                                    int N, int K) {
    __shared__ short As[2][4096];
    __shared__ short Bs[2][4096];
    int tid = threadIdx.x, lane = tid & 63, wid = tid >> 6;
    int bid = blockIdx.x;
    int chunk = (N >> 7) << 1;
    int swz = (bid & 7) * chunk + (bid >> 3);
    int bn = (swz >> 4) << 7;
    int bm = (swz & 15) << 7;
    int wr = (wid >> 1) << 6, wc = (wid & 1) << 6;
    f32x4 acc[4][4] = {};
    int rA = tid >> 2, sA = tid & 3;
    int q = lane >> 4, rr = lane & 15;

    auto STAGE = [&](int b, int k0) {
#pragma unroll
        for (int i = 0; i < 2; i++) {
            int r = rA + (i << 6);
            int gc = k0 + ((sA ^ ((r >> 1) & 3)) << 3);
            char* dstA = (char*)As + b * 8192 + (i << 12) + (wid << 10);
            char* dstB = (char*)Bs + b * 8192 + (i << 12) + (wid << 10);
            gload_lds16(A  + (size_t)(bm + r) * K + gc, dstA);
            gload_lds16(Wt + (size_t)(bn + r) * K + gc, dstB);
        }
    };

    STAGE(0, 0);
    int cur = 0;
    for (int k0 = 0; k0 < K; k0 += 32) {
        if (k0 + 32 < K) {
            STAGE(cur ^ 1, k0 + 32);
            asm volatile("s_waitcnt vmcnt(4)" ::: "memory");
        } else {
            asm volatile("s_waitcnt vmcnt(0)" ::: "memory");
        }
        __builtin_amdgcn_s_barrier();
        __builtin_amdgcn_sched_barrier(0);
        bf16x8 af[4], bfr[4];
#pragma unroll
        for (int m = 0; m < 4; m++) {
            int rowa = wr + (m << 4) + rr;
            af[m]  = *(const bf16x8*)((const char*)As + cur * 8192 + rowa * 64 + ((q ^ ((rowa >> 1) & 3)) << 4));
            int rowb = wc + (m << 4) + rr;
            bfr[m] = *(const bf16x8*)((const char*)Bs + cur * 8192 + rowb * 64 + ((q ^ ((rowb >> 1) & 3)) << 4));
        }
#pragma unroll
        for (int m = 0; m < 4; m++)
#pragma unroll
            for (int n = 0; n < 4; n++)
                acc[m][n] = __builtin_amdgcn_mfma_f32_16x16x32_bf16(bfr[n], af[m], acc[m][n], 0, 0, 0);
        __builtin_amdgcn_sched_barrier(0);
        __builtin_amdgcn_s_barrier();
        cur ^= 1;
    }

    int cl = lane & 15, g = lane >> 4;
#pragma unroll
    for (int m = 0; m < 4; m++) {
        int row = bm + wr + (m << 4) + cl;
#pragma unroll
        for (int n = 0; n < 4; n++) {
            int col0 = bn + wc + (n << 4) + (g << 2);
            float4 bv = *(const float4*)&bias[col0];
            f32x4 v = acc[m][n];
            v[0] += bv.x; v[1] += bv.y; v[2] += bv.z; v[3] += bv.w;
            if (RES) {
                float4 rv = *(const float4*)&res[(size_t)row * N + col0];
                v[0] += rv.x; v[1] += rv.y; v[2] += rv.z; v[3] += rv.w;
            }
            if (ACT) {
#pragma unroll
                for (int j = 0; j < 4; j++)
                    v[j] = v[j] / (1.0f + __expf(-1.5957691216057308f * (v[j] + 0.044715f * v[j] * v[j] * v[j])));
            }
            if (OBF) {
                s16x4 pk;
#pragma unroll
                for (int j = 0; j < 4; j++) {
                    bf16 t = __float2bfloat16(v[j]);
                    pk[j] = *reinterpret_cast<short*>(&t);
                }
                *(s16x4*)&outb[(size_t)row * N + col0] = pk;
            } else {
                *(f32x4*)&outf[(size_t)row * N + col0] = v;
            }
        }
    }
}

// ---------------- split-K MFMA GEMM (1D grid, XCD-chunked) ----------------
__global__ __launch_bounds__(256) void mgemmp_kernel(const short* __restrict__ A,
                                                     const short* __restrict__ Wt,
                                                     float* __restrict__ partial,
                                                     int N, int Kc, int Kstride) {
    __shared__ short As[2][4096];
    __shared__ short Bs[2][4096];
    int tid = threadIdx.x, lane = tid & 63, wid = tid >> 6;
    int bid = blockIdx.x;
    int per_z = (N >> 7) << 4;
    int chunk = (per_z * KSPLIT) >> 3;
    int swz = (bid & 7) * chunk + (bid >> 3);
    int z = swz / per_z;
    int rem = swz - z * per_z;
    int bn = (rem >> 4) << 7;
    int bm = (rem & 15) << 7;
    const short* Ab  = A  + (size_t)z * Kc;
    const short* Wb  = Wt + (size_t)z * Kc;
    int wr = (wid >> 1) << 6, wc = (wid & 1) << 6;
    f32x4 acc[4][4] = {};
    int rA = tid >> 2, sA = tid & 3;
    int q = lane >> 4, rr = lane & 15;

    auto STAGE = [&](int b, int k0) {
#pragma unroll
        for (int i = 0; i < 2; i++) {
            int r = rA + (i << 6);
            int gc = k0 + ((sA ^ ((r >> 1) & 3)) << 3);
            char* dstA = (char*)As + b * 8192 + (i << 12) + (wid << 10);
            char* dstB = (char*)Bs + b * 8192 + (i << 12) + (wid << 10);
            gload_lds16(Ab + (size_t)(bm + r) * Kstride + gc, dstA);
            gload_lds16(Wb + (size_t)(bn + r) * Kstride + gc, dstB);
        }
    };

    STAGE(0, 0);
    int cur = 0;
    for (int k0 = 0; k0 < Kc; k0 += 32) {
        if (k0 + 32 < Kc) {
            STAGE(cur ^ 1, k0 + 32);
            asm volatile("s_waitcnt vmcnt(4)" ::: "memory");
        } else {
            asm volatile("s_waitcnt vmcnt(0)" ::: "memory");
        }
        __builtin_amdgcn_s_barrier();
        __builtin_amdgcn_sched_barrier(0);
        bf16x8 af[4], bfr[4];
#pragma unroll
        for (int m = 0; m < 4; m++) {
            int rowa = wr + (m << 4) + rr;
            af[m]  = *(const bf16x8*)((const char*)As + cur * 8192 + rowa * 64 + ((q ^ ((rowa >> 1) & 3)) << 4));
            int rowb = wc + (m << 4) + rr;
            bfr[m] = *(const bf16x8*)((const char*)Bs + cur * 8192 + rowb * 64 + ((q ^ ((rowb >> 1) & 3)) << 4));
        }
#pragma unroll
        for (int m = 0; m < 4; m++)
#pragma unroll
            for (int n = 0; n < 4; n++)
                acc[m][n] = __builtin_amdgcn_mfma_f32_16x16x32_bf16(bfr[n], af[m], acc[m][n], 0, 0, 0);
        __builtin_amdgcn_sched_barrier(0);
        __builtin_amdgcn_s_barrier();
        cur ^= 1;
    }

    float* outz = partial + (size_t)z * SEQ * DMODEL;
    int cl = lane & 15, g = lane >> 4;
#pragma unroll
    for (int m = 0; m < 4; m++) {
        int row = bm + wr + (m << 4) + cl;
#pragma unroll
        for (int n = 0; n < 4; n++) {
            int col0 = bn + wc + (n << 4) + (g << 2);
            *(f32x4*)&outz[(size_t)row * N + col0] = acc[m][n];
        }
    }
}

// ---------------- head GEMM: 256x128 tile, 8 waves, 3-buffer + vmcnt(6), fused no-max sum-exp ----------------
__global__ __launch_bounds__(512) void head_kernel(const short* __restrict__ A,
                                                   const short* __restrict__ Wt,
                                                   const float* __restrict__ bias,
                                                   float* __restrict__ out,
                                                   float* __restrict__ ps) {
    __shared__ short As[3][8192];   // 48 KB
    __shared__ short Bs[3][4096];   // 24 KB
    __shared__ float lsum[256][2];
    constexpr int K = DMODEL;
    constexpr int NKT = K / 32;     // 24
    int bid = blockIdx.x;
    int swz = (bid & 7) * 393 + (bid >> 3);
    int bm = (swz & 7) << 8;
    int bxp = swz >> 3;
    int bn = bxp << 7;
    int tid = threadIdx.x, lane = tid & 63, wid = tid >> 6;
    int wr = (wid >> 1) << 6;
    int wc = (wid & 1) << 6;
    f32x4 acc[4][4] = {};
    int rA = tid >> 2, sA = tid & 3;
    int q = lane >> 4, rr = lane & 15;

    auto STAGE = [&](int b, int kt) {
        int k0 = kt << 5;
#pragma unroll
        for (int i = 0; i < 2; i++) {
            int r = rA + (i << 7);
            int gc = k0 + ((sA ^ ((r >> 1) & 3)) << 3);
            gload_lds16(A + (size_t)(bm + r) * K + gc, (char*)As + b * 16384 + (i << 13) + tid * 16);
        }
        {
            int gc = k0 + ((sA ^ ((rA >> 1) & 3)) << 3);
            gload_lds16(Wt + (size_t)(bn + rA) * K + gc, (char*)Bs + b * 8192 + tid * 16);
        }
    };

    STAGE(0, 0);
    STAGE(1, 1);
    for (int kt = 0; kt < NKT; kt++) {
        int b = kt % 3;
        if (kt + 2 < NKT) {
            STAGE((kt + 2) % 3, kt + 2);
            asm volatile("s_waitcnt vmcnt(6)" ::: "memory");
        } else if (kt == NKT - 2) {
            asm volatile("s_waitcnt vmcnt(3)" ::: "memory");
        } else {
            asm volatile("s_waitcnt vmcnt(0)" ::: "memory");
        }
        __builtin_amdgcn_s_barrier();
        __builtin_amdgcn_sched_barrier(0);
        bf16x8 af[4], bfr[4];
#pragma unroll
        for (int m = 0; m < 4; m++) {
            int rowa = wr + (m << 4) + rr;
            af[m]  = *(const bf16x8*)((const char*)As + b * 16384 + rowa * 64 + ((q ^ ((rowa >> 1) & 3)) << 4));
            int rowb = wc + (m << 4) + rr;
            bfr[m] = *(const bf16x8*)((const char*)Bs + b * 8192 + rowb * 64 + ((q ^ ((rowb >> 1) & 3)) << 4));
        }
#pragma unroll
        for (int m = 0; m < 4; m++)
#pragma unroll
            for (int n = 0; n < 4; n++)
                acc[m][n] = __builtin_amdgcn_mfma_f32_16x16x32_bf16(bfr[n], af[m], acc[m][n], 0, 0, 0);
        __builtin_amdgcn_sched_barrier(0);
        __builtin_amdgcn_s_barrier();
    }

    int cl = lane & 15, g = lane >> 4;
#pragma unroll
    for (int m = 0; m < 4; m++) {
        int row = bm + wr + (m << 4) + cl;
        float s = 0.f;
#pragma unroll
        for (int n = 0; n < 4; n++) {
            int col0 = bn + wc + (n << 4) + (g << 2);
            f32x4 v = acc[m][n];
            if (col0 + 3 < NV) {
                float4 bv = *(const float4*)&bias[col0];
                v[0] += bv.x; v[1] += bv.y; v[2] += bv.z; v[3] += bv.w;
                *(f32x4*)&out[(size_t)row * NV + col0] = v;
                s += __expf(v[0]) + __expf(v[1]) + __expf(v[2]) + __expf(v[3]);
            } else {
#pragma unroll
                for (int j = 0; j < 4; j++) {
                    if (col0 + j < NV) {
                        float u = v[j] + bias[col0 + j];
                        out[(size_t)row * NV + col0 + j] = u;
                        s += __expf(u);
                    }
                }
            }
        }
        s += __shfl_xor(s, 16, 64);
        s += __shfl_xor(s, 32, 64);
        if (g == 0) lsum[wr + (m << 4) + cl][wid & 1] = s;
    }
    __syncthreads();
    if (tid < 256)
        ps[(size_t)(bm + tid) * NB + bxp] = lsum[tid][0] + lsum[tid][1];
}

// ---------------- LSE reduce + NLL: nll[row] = log(sum ps) - logit[row][target] ----------------
__global__ __launch_bounds__(256) void lsered_kernel(const float* __restrict__ ps,
                                                     const float* __restrict__ logits,
                                                     const int* __restrict__ targets,
                                                     float* __restrict__ nll) {
    int row = (blockIdx.x << 2) + (threadIdx.x >> 6);
    int lane = threadIdx.x & 63;
    const float* psr = ps + (size_t)row * NB;
    float s = 0.f;
    for (int j = lane; j < NB; j += 64) s += psr[j];
#pragma unroll
    for (int off = 32; off; off >>= 1) s += __shfl_xor(s, off, 64);
    if (lane == 0) nll[row] = logf(s) - logits[(size_t)row * NV + targets[row]];
}

// ---------------- MFMA flash attention: Q-tile 64, KV-tile 128, fixed-shift softmax ----------------
__global__ __launch_bounds__(256) void attn_kernel(const short* __restrict__ qkv,
                                                   bf16* __restrict__ o) {
    __shared__ short Ks[8192];
    __shared__ short Vt[8192];
    __shared__ short Ps[8192];
    int qt = gridDim.x - 1 - blockIdx.x;
    int h = blockIdx.y, tid = threadIdx.x;
    int lane = tid & 63, w = tid >> 6;
    int g = lane >> 4, c = lane & 15;
    int q0 = qt << 6;
    int nkt = (qt >> 1) + 1;

    bf16x8 qa[2];
    {
        const short* src = qkv + (size_t)(q0 + w * 16 + c) * 2304 + h * 64 + g * 8;
        qa[0] = *(const bf16x8*)src;
        qa[1] = *(const bf16x8*)(src + 32);
    }
    float l_i[4] = {};
    f32x4 oacc[4] = {};

    for (int kt = 0; kt < nkt; kt++) {
        bool last = (kt == nkt - 1);
        __syncthreads();
#pragma unroll
        for (int i = 0; i < 4; i++) {
            int r = (tid >> 3) + i * 32;
            int gslot = (tid & 7) ^ ((r & 7) ^ ((r >> 3) & 7));
            gload_lds16(qkv + (size_t)(kt * 128 + r) * 2304 + 768 + h * 64 + gslot * 8,
                        (char*)Ks + tid * 16 + i * 4096);
        }
#pragma unroll
        for (int ci = 0; ci < 4; ci++) {
            int rv = (tid >> 3) + ci * 32;
            bf16x8 vv = *(const bf16x8*)(qkv + (size_t)(kt * 128 + rv) * 2304 + 1536 + h * 64 + (tid & 7) * 8);
            int slot = rv >> 3;
#pragma unroll
            for (int j = 0; j < 8; j++) {
                int row = (tid & 7) * 8 + j;
                int sp = slot ^ ((row & 7) ^ ((row >> 3) & 7));
                Vt[row * 128 + sp * 8 + (rv & 7)] = vv[j];
            }
        }
        __syncthreads();

        f32x4 sacc[8] = {};
#pragma unroll
        for (int n = 0; n < 8; n++) {
#pragma unroll
            for (int ks = 0; ks < 2; ks++) {
                int row = n * 16 + c;
                int sp = (ks * 4 + g) ^ ((row & 7) ^ ((row >> 3) & 7));
                bf16x8 kf = *(const bf16x8*)(Ks + row * 64 + sp * 8);
                sacc[n] = __builtin_amdgcn_mfma_f32_16x16x32_bf16(qa[ks], kf, sacc[n], 0, 0, 0);
            }
        }
        if (!last) {
#pragma unroll
            for (int i = 0; i < 4; i++) {
                float rs = 0.f;
                int row = g * 4 + i;
                int sw = (row & 7) ^ (row >> 3);
#pragma unroll
                for (int n = 0; n < 8; n++) {
                    float p = __expf(sacc[n][i] * 0.125f);
                    rs += p;
                    int sp = (2 * n + (c >> 3)) ^ sw;
                    bf16 pb = __float2bfloat16(p);
                    Ps[w * 2048 + row * 128 + sp * 8 + (c & 7)] = *reinterpret_cast<short*>(&pb);
                }
                rs += __shfl_xor(rs, 1, 16);
                rs += __shfl_xor(rs, 2, 16);
                rs += __shfl_xor(rs, 4, 16);
                rs += __shfl_xor(rs, 8, 16);
                l_i[i] += rs;
            }
        } else {
#pragma unroll
            for (int i = 0; i < 4; i++) {
                float rs = 0.f;
                int qrow = q0 + w * 16 + g * 4 + i;
                int row = g * 4 + i;
                int sw = (row & 7) ^ (row >> 3);
#pragma unroll
                for (int n = 0; n < 8; n++) {
                    float p = __expf(sacc[n][i] * 0.125f);
                    if (kt * 128 + n * 16 + c > qrow) p = 0.f;
                    rs += p;
                    int sp = (2 * n + (c >> 3)) ^ sw;
                    bf16 pb = __float2bfloat16(p);
                    Ps[w * 2048 + row * 128 + sp * 8 + (c & 7)] = *reinterpret_cast<short*>(&pb);
                }
                rs += __shfl_xor(rs, 1, 16);
                rs += __shfl_xor(rs, 2, 16);
                rs += __shfl_xor(rs, 4, 16);
                rs += __shfl_xor(rs, 8, 16);
                l_i[i] += rs;
            }
        }
        bf16x8 pa[4];
#pragma unroll
        for (int ks = 0; ks < 4; ks++) {
            int sw = (c & 7) ^ (c >> 3);
            int sp = (ks * 4 + g) ^ sw;
            pa[ks] = *(const bf16x8*)(Ps + w * 2048 + c * 128 + sp * 8);
        }
#pragma unroll
        for (int n = 0; n < 4; n++) {
#pragma unroll
            for (int ks = 0; ks < 4; ks++) {
                int row = n * 16 + c;
                int sp = (ks * 4 + g) ^ ((row & 7) ^ ((row >> 3) & 7));
                bf16x8 vf = *(const bf16x8*)(Vt + row * 128 + sp * 8);
                oacc[n] = __builtin_amdgcn_mfma_f32_16x16x32_bf16(pa[ks], vf, oacc[n], 0, 0, 0);
            }
        }
    }
#pragma unroll
    for (int i = 0; i < 4; i++) {
        float inv = 1.0f / l_i[i];
#pragma unroll
        for (int n = 0; n < 4; n++)
            o[(size_t)(q0 + w * 16 + g * 4 + i) * DMODEL + h * 64 + n * 16 + c] =
                __float2bfloat16(oacc[n][i] * inv);
    }
}

// ---------------- loss = mean(nll) ----------------
__global__ __launch_bounds__(256) void loss_kernel(const float* __restrict__ nll,
                                                   float* __restrict__ out) {
    __shared__ float red[4];
    int tid = threadIdx.x;
    float acc = 0.f;
    for (int t = tid; t < SEQ; t += 256) acc += nll[t];
#pragma unroll
    for (int off = 32; off; off >>= 1) acc += __shfl_down(acc, off, 64);
    int wid = tid >> 6, lane = tid & 63;
    if (lane == 0) red[wid] = acc;
    __syncthreads();
    if (tid == 0) out[0] = (red[0] + red[1] + red[2] + red[3]) * (1.0f / SEQ);
}

extern "C" void kernel_launch(void* const* d_in, const int* in_sizes, int n_in,
                              void* d_out, int out_size, void* d_ws, size_t ws_size,
                              hipStream_t stream) {
    const int*   idx         = (const int*)d_in[0];
    const int*   targets     = (const int*)d_in[1];
    const float* wte         = (const float*)d_in[2];
    const float* wpe         = (const float*)d_in[3];
    const float* ln1_w       = (const float*)d_in[4];
    const float* ln1_b       = (const float*)d_in[5];
    const float* attn_w      = (const float*)d_in[6];
    const float* attn_b      = (const float*)d_in[7];
    const float* attn_proj_w = (const float*)d_in[8];
    const float* attn_proj_b = (const float*)d_in[9];
    const float* ln2_w       = (const float*)d_in[10];
    const float* ln2_b       = (const float*)d_in[11];
    const float* fc_w        = (const float*)d_in[12];
    const float* fc_b        = (const float*)d_in[13];
    const float* mlp_proj_w  = (const float*)d_in[14];
    const float* mlp_proj_b  = (const float*)d_in[15];
    const float* lnf_w       = (const float*)d_in[16];
    const float* lnf_b       = (const float*)d_in[17];
    const float* head_w      = (const float*)d_in[18];
    const float* head_b      = (const float*)d_in[19];

    float* logits = (float*)d_out;
    float* loss   = logits + (size_t)SEQ * NV;

    char* p = (char*)d_ws;
    float* x    = (float*)p;  p += (size_t)SEQ * DMODEL * 4;
    bf16*  h    = (bf16*)p;   p += (size_t)SEQ * DMODEL * 2;
    bf16*  o    = (bf16*)p;   p += (size_t)SEQ * DMODEL * 2;
    bf16*  qkvb = (bf16*)p;   p += (size_t)SEQ * 2304 * 2;
    bf16*  fcb  = (bf16*)p;   p += (size_t)SEQ * 3072 * 2;
    float* nll  = (float*)p;  p += (size_t)SEQ * 4;
    float* ps   = (float*)p;  p += (size_t)SEQ * NB * 4;
    bf16*  Wt   = (bf16*)p;

    bf16* wtA = Wt;
    bf16* wtP = wtA + (size_t)4 * 2304 * 768;
    bf16* wtF = wtP + (size_t)4 * 768 * 768;
    bf16* wtM = wtF + (size_t)4 * 3072 * 768;
    float* kscr = (float*)(wtM + (size_t)4 * 768 * 3072);

    embed_kernel<<<SEQ, 192, 0, stream>>>(idx, wte, wpe, x);

    transpb_kernel<<<dim3(2304 / 64, DMODEL / 64, 4), 256, 0, stream>>>(
        attn_w, wtA, DMODEL, 2304, (size_t)DMODEL * 2304, (size_t)2304 * DMODEL);
    transpb_kernel<<<dim3(DMODEL / 64, DMODEL / 64, 4), 256, 0, stream>>>(
        attn_proj_w, wtP, DMODEL, DMODEL, (size_t)DMODEL * DMODEL, (size_t)DMODEL * DMODEL);
    transpb_kernel<<<dim3(3072 / 64, DMODEL / 64, 4), 256, 0, stream>>>(
        fc_w, wtF, DMODEL, 3072, (size_t)DMODEL * 3072, (size_t)3072 * DMODEL);
    transpb_kernel<<<dim3(DMODEL / 64, 3072 / 64, 4), 256, 0, stream>>>(
        mlp_proj_w, wtM, 3072, DMODEL, (size_t)3072 * DMODEL, (size_t)DMODEL * 3072);

    ln_kernel<<<SEQ, 256, 0, stream>>>(x, ln1_w, ln1_b, h);
    for (int l = 0; l < NLAYER; l++) {
        mgemm_kernel<0, 0, 1><<<dim3((2304 / 128) * 16), 256, 0, stream>>>(
            (const short*)h, (const short*)(wtA + (size_t)l * 2304 * DMODEL),
            attn_b + l * 2304, nullptr, nullptr, qkvb, 2304, DMODEL);
        attn_kernel<<<dim3(SEQ / 64, NHEAD), 256, 0, stream>>>((const short*)qkvb, o);
        mgemmp_kernel<<<dim3((DMODEL / 128) * 16 * KSPLIT), 256, 0, stream>>>(
            (const short*)o, (const short*)(wtP + (size_t)l * DMODEL * DMODEL),
            kscr, DMODEL, DMODEL / KSPLIT, DMODEL);
        kredln_kernel<<<SEQ, 192, 0, stream>>>(
            kscr, attn_proj_b + l * DMODEL, x, ln2_w + l * DMODEL, ln2_b + l * DMODEL, h);
        mgemm_kernel<1, 0, 1><<<dim3((3072 / 128) * 16), 256, 0, stream>>>(
            (const short*)h, (const short*)(wtF + (size_t)l * 3072 * DMODEL),
            fc_b + l * 3072, nullptr, nullptr, fcb, 3072, DMODEL);
        mgemmp_kernel<<<dim3((DMODEL / 128) * 16 * KSPLIT), 256, 0, stream>>>(
            (const short*)fcb, (const short*)(wtM + (size_t)l * DMODEL * 3072),
            kscr, DMODEL, 3072 / KSPLIT, 3072);
        const float* nw = (l == NLAYER - 1) ? lnf_w : ln1_w + (l + 1) * DMODEL;
        const float* nb = (l == NLAYER - 1) ? lnf_b : ln1_b + (l + 1) * DMODEL;
        kredln_kernel<<<SEQ, 192, 0, stream>>>(
            kscr, mlp_proj_b + l * DMODEL, x, nw, nb, h);
    }

    transpb_kernel<<<dim3(NVPAD / 64, DMODEL / 64, 1), 256, 0, stream>>>(
        head_w, Wt, DMODEL, NV, 0, 0);
    head_kernel<<<dim3(8 * 393), 512, 0, stream>>>(
        (const short*)h, (const short*)Wt, head_b, logits, ps);
    lsered_kernel<<<SEQ / 4, 256, 0, stream>>>(ps, logits, targets, nll);
    loss_kernel<<<1, 256, 0, stream>>>(nll, loss);
}

// Round 20
// 1038.729 us; speedup vs baseline: 1.0109x; 1.0109x over previous
//
#include <hip/hip_runtime.h>
#include <hip/hip_bf16.h>
#include <math.h>

using bf16   = __hip_bfloat16;
using f32x4  = __attribute__((ext_vector_type(4))) float;
using bf16x8 = __attribute__((ext_vector_type(8))) short;
using s16x4  = __attribute__((ext_vector_type(4))) short;

constexpr int SEQ    = 2048;
constexpr int DMODEL = 768;
constexpr int NHEAD  = 12;
constexpr int NV     = 50257;
constexpr int NVPAD  = 50304;
constexpr int NB     = NVPAD / 128;   // 393 column panels
constexpr int NLAYER = 4;
constexpr int KSPLIT = 3;

__device__ __forceinline__ void gload_lds16(const void* g, void* s) {
    __builtin_amdgcn_global_load_lds((const __attribute__((address_space(1))) void*)g,
                                     (__attribute__((address_space(3))) void*)s, 16, 0, 0);
}

// ---------------- embedding ----------------
__global__ __launch_bounds__(192) void embed_kernel(const int* __restrict__ idx,
                                                    const float* __restrict__ wte,
                                                    const float* __restrict__ wpe,
                                                    float* __restrict__ x) {
    int t = blockIdx.x;
    int tok = idx[t];
    const float4* a = (const float4*)(wte + (size_t)tok * DMODEL);
    const float4* b = (const float4*)(wpe + (size_t)t * DMODEL);
    float4* o = (float4*)(x + (size_t)t * DMODEL);
    int d = threadIdx.x;
    float4 u = a[d], v = b[d];
    u.x += v.x; u.y += v.y; u.z += v.z; u.w += v.w;
    o[d] = u;
}

// ---------------- layernorm: fp32 in, bf16 out ----------------
__global__ __launch_bounds__(256) void ln_kernel(const float* __restrict__ x,
                                                 const float* __restrict__ w,
                                                 const float* __restrict__ b,
                                                 bf16* __restrict__ out) {
    __shared__ float red[8];
    int row = blockIdx.x, tid = threadIdx.x;
    const float* xr = x + (size_t)row * DMODEL;
    float v[3];
    float s = 0.f, ss = 0.f;
#pragma unroll
    for (int j = 0; j < 3; j++) {
        v[j] = xr[tid + j * 256];
        s += v[j];
        ss += v[j] * v[j];
    }
#pragma unroll
    for (int off = 32; off; off >>= 1) {
        s  += __shfl_down(s,  off, 64);
        ss += __shfl_down(ss, off, 64);
    }
    int wid = tid >> 6, lane = tid & 63;
    if (lane == 0) { red[wid] = s; red[4 + wid] = ss; }
    __syncthreads();
    s  = red[0] + red[1] + red[2] + red[3];
    ss = red[4] + red[5] + red[6] + red[7];
    float mean = s * (1.0f / DMODEL);
    float var  = ss * (1.0f / DMODEL) - mean * mean;
    float rstd = rsqrtf(var + 1e-5f);
#pragma unroll
    for (int j = 0; j < 3; j++) {
        int d = tid + j * 256;
        out[(size_t)row * DMODEL + d] = __float2bfloat16((v[j] - mean) * rstd * w[d] + b[d]);
    }
}

// ---------------- fused split-K reduce + layernorm ----------------
__global__ __launch_bounds__(192) void kredln_kernel(const float* __restrict__ partial,
                                                     const float* __restrict__ gbias,
                                                     float* __restrict__ x,
                                                     const float* __restrict__ lnw,
                                                     const float* __restrict__ lnb,
                                                     bf16* __restrict__ h) {
    __shared__ float red[6];
    int row = blockIdx.x, t = threadIdx.x;
    size_t off = (size_t)row * DMODEL + t * 4;
    f32x4 v = *(f32x4*)&x[off];
    float4 b = *(const float4*)&gbias[t * 4];
    v[0] += b.x; v[1] += b.y; v[2] += b.z; v[3] += b.w;
#pragma unroll
    for (int z = 0; z < KSPLIT; z++) {
        f32x4 p = *(const f32x4*)&partial[(size_t)z * SEQ * DMODEL + off];
        v[0] += p[0]; v[1] += p[1]; v[2] += p[2]; v[3] += p[3];
    }
    *(f32x4*)&x[off] = v;
    float s  = v[0] + v[1] + v[2] + v[3];
    float ss = v[0] * v[0] + v[1] * v[1] + v[2] * v[2] + v[3] * v[3];
#pragma unroll
    for (int o2 = 32; o2; o2 >>= 1) {
        s  += __shfl_down(s,  o2, 64);
        ss += __shfl_down(ss, o2, 64);
    }
    int wid = t >> 6, lane = t & 63;
    if (lane == 0) { red[wid] = s; red[3 + wid] = ss; }
    __syncthreads();
    s  = red[0] + red[1] + red[2];
    ss = red[3] + red[4] + red[5];
    float mean = s * (1.0f / DMODEL);
    float var  = ss * (1.0f / DMODEL) - mean * mean;
    float rstd = rsqrtf(var + 1e-5f);
    float4 w4 = *(const float4*)&lnw[t * 4];
    float4 b4 = *(const float4*)&lnb[t * 4];
    s16x4 pk;
    {
        bf16 t0 = __float2bfloat16((v[0] - mean) * rstd * w4.x + b4.x);
        bf16 t1 = __float2bfloat16((v[1] - mean) * rstd * w4.y + b4.y);
        bf16 t2 = __float2bfloat16((v[2] - mean) * rstd * w4.z + b4.z);
        bf16 t3 = __float2bfloat16((v[3] - mean) * rstd * w4.w + b4.w);
        pk[0] = *reinterpret_cast<short*>(&t0);
        pk[1] = *reinterpret_cast<short*>(&t1);
        pk[2] = *reinterpret_cast<short*>(&t2);
        pk[3] = *reinterpret_cast<short*>(&t3);
    }
    *(s16x4*)&h[off] = pk;
}

// ---------------- batched transpose + fp32->bf16: W[K][N] -> Wt[Npad][K] ----------------
__global__ __launch_bounds__(256) void transpb_kernel(const float* __restrict__ W,
                                                      bf16* __restrict__ Wt,
                                                      int K, int N,
                                                      size_t wstride, size_t tstride) {
    __shared__ float t[64][65];
    int l = blockIdx.z;
    W  += (size_t)l * wstride;
    Wt += (size_t)l * tstride;
    int n0 = blockIdx.x << 6, k0 = blockIdx.y << 6;
    int tid = threadIdx.x;
#pragma unroll
    for (int i = 0; i < 16; i++) {
        int id = tid + (i << 8);
        int r = id >> 6, c = id & 63;
        int n = n0 + c;
        t[r][c] = (n < N) ? W[(size_t)(k0 + r) * N + n] : 0.0f;
    }
    __syncthreads();
#pragma unroll
    for (int i = 0; i < 16; i++) {
        int id = tid + (i << 8);
        int nr = id >> 6, kc = id & 63;
        Wt[(size_t)(n0 + nr) * K + k0 + kc] = __float2bfloat16(t[kc][nr]);
    }
}

// ---------------- MFMA GEMM (1D grid, XCD-chunked): C = epi(A @ Wt^T) ----------------
template <int ACT, int RES, int OBF>
__global__ __launch_bounds__(256) void mgemm_kernel(const short* __restrict__ A,
                                                    const short* __restrict__ Wt,
                                                    const float* __restrict__ bias,
                                                    const float* __restrict__ res,
                                                    float* __restrict__ outf,
                                                    bf16* __restrict__ outb,
                                                    int N, int K) {
    __shared__ short As[2][4096];
    __shared__ short Bs[2][4096];
    int tid = threadIdx.x, lane = tid & 63, wid = tid >> 6;
    int bid = blockIdx.x;
    int chunk = (N >> 7) << 1;
    int swz = (bid & 7) * chunk + (bid >> 3);
    int bn = (swz >> 4) << 7;
    int bm = (swz & 15) << 7;
    int wr = (wid >> 1) << 6, wc = (wid & 1) << 6;
    f32x4 acc[4][4] = {};
    int rA = tid >> 2, sA = tid & 3;
    int q = lane >> 4, rr = lane & 15;

    auto STAGE = [&](int b, int k0) {
#pragma unroll
        for (int i = 0; i < 2; i++) {
            int r = rA + (i << 6);
            int gc = k0 + ((sA ^ ((r >> 1) & 3)) << 3);
            char* dstA = (char*)As + b * 8192 + (i << 12) + (wid << 10);
            char* dstB = (char*)Bs + b * 8192 + (i << 12) + (wid << 10);
            gload_lds16(A  + (size_t)(bm + r) * K + gc, dstA);
            gload_lds16(Wt + (size_t)(bn + r) * K + gc, dstB);
        }
    };

    STAGE(0, 0);
    int cur = 0;
    for (int k0 = 0; k0 < K; k0 += 32) {
        if (k0 + 32 < K) {
            STAGE(cur ^ 1, k0 + 32);
            asm volatile("s_waitcnt vmcnt(4)" ::: "memory");
        } else {
            asm volatile("s_waitcnt vmcnt(0)" ::: "memory");
        }
        __builtin_amdgcn_s_barrier();
        __builtin_amdgcn_sched_barrier(0);
        bf16x8 af[4], bfr[4];
#pragma unroll
        for (int m = 0; m < 4; m++) {
            int rowa = wr + (m << 4) + rr;
            af[m]  = *(const bf16x8*)((const char*)As + cur * 8192 + rowa * 64 + ((q ^ ((rowa >> 1) & 3)) << 4));
            int rowb = wc + (m << 4) + rr;
            bfr[m] = *(const bf16x8*)((const char*)Bs + cur * 8192 + rowb * 64 + ((q ^ ((rowb >> 1) & 3)) << 4));
        }
#pragma unroll
        for (int m = 0; m < 4; m++)
#pragma unroll
            for (int n = 0; n < 4; n++)
                acc[m][n] = __builtin_amdgcn_mfma_f32_16x16x32_bf16(bfr[n], af[m], acc[m][n], 0, 0, 0);
        __builtin_amdgcn_sched_barrier(0);
        __builtin_amdgcn_s_barrier();
        cur ^= 1;
    }

    int cl = lane & 15, g = lane >> 4;
#pragma unroll
    for (int m = 0; m < 4; m++) {
        int row = bm + wr + (m << 4) + cl;
#pragma unroll
        for (int n = 0; n < 4; n++) {
            int col0 = bn + wc + (n << 4) + (g << 2);
            float4 bv = *(const float4*)&bias[col0];
            f32x4 v = acc[m][n];
            v[0] += bv.x; v[1] += bv.y; v[2] += bv.z; v[3] += bv.w;
            if (RES) {
                float4 rv = *(const float4*)&res[(size_t)row * N + col0];
                v[0] += rv.x; v[1] += rv.y; v[2] += rv.z; v[3] += rv.w;
            }
            if (ACT) {
#pragma unroll
                for (int j = 0; j < 4; j++)
                    v[j] = v[j] / (1.0f + __expf(-1.5957691216057308f * (v[j] + 0.044715f * v[j] * v[j] * v[j])));
            }
            if (OBF) {
                s16x4 pk;
#pragma unroll
                for (int j = 0; j < 4; j++) {
                    bf16 t = __float2bfloat16(v[j]);
                    pk[j] = *reinterpret_cast<short*>(&t);
                }
                *(s16x4*)&outb[(size_t)row * N + col0] = pk;
            } else {
                *(f32x4*)&outf[(size_t)row * N + col0] = v;
            }
        }
    }
}

// ---------------- split-K MFMA GEMM (1D grid, XCD-chunked) ----------------
__global__ __launch_bounds__(256) void mgemmp_kernel(const short* __restrict__ A,
                                                     const short* __restrict__ Wt,
                                                     float* __restrict__ partial,
                                                     int N, int Kc, int Kstride) {
    __shared__ short As[2][4096];
    __shared__ short Bs[2][4096];
    int tid = threadIdx.x, lane = tid & 63, wid = tid >> 6;
    int bid = blockIdx.x;
    int per_z = (N >> 7) << 4;
    int chunk = (per_z * KSPLIT) >> 3;
    int swz = (bid & 7) * chunk + (bid >> 3);
    int z = swz / per_z;
    int rem = swz - z * per_z;
    int bn = (rem >> 4) << 7;
    int bm = (rem & 15) << 7;
    const short* Ab  = A  + (size_t)z * Kc;
    const short* Wb  = Wt + (size_t)z * Kc;
    int wr = (wid >> 1) << 6, wc = (wid & 1) << 6;
    f32x4 acc[4][4] = {};
    int rA = tid >> 2, sA = tid & 3;
    int q = lane >> 4, rr = lane & 15;

    auto STAGE = [&](int b, int k0) {
#pragma unroll
        for (int i = 0; i < 2; i++) {
            int r = rA + (i << 6);
            int gc = k0 + ((sA ^ ((r >> 1) & 3)) << 3);
            char* dstA = (char*)As + b * 8192 + (i << 12) + (wid << 10);
            char* dstB = (char*)Bs + b * 8192 + (i << 12) + (wid << 10);
            gload_lds16(Ab + (size_t)(bm + r) * Kstride + gc, dstA);
            gload_lds16(Wb + (size_t)(bn + r) * Kstride + gc, dstB);
        }
    };

    STAGE(0, 0);
    int cur = 0;
    for (int k0 = 0; k0 < Kc; k0 += 32) {
        if (k0 + 32 < Kc) {
            STAGE(cur ^ 1, k0 + 32);
            asm volatile("s_waitcnt vmcnt(4)" ::: "memory");
        } else {
            asm volatile("s_waitcnt vmcnt(0)" ::: "memory");
        }
        __builtin_amdgcn_s_barrier();
        __builtin_amdgcn_sched_barrier(0);
        bf16x8 af[4], bfr[4];
#pragma unroll
        for (int m = 0; m < 4; m++) {
            int rowa = wr + (m << 4) + rr;
            af[m]  = *(const bf16x8*)((const char*)As + cur * 8192 + rowa * 64 + ((q ^ ((rowa >> 1) & 3)) << 4));
            int rowb = wc + (m << 4) + rr;
            bfr[m] = *(const bf16x8*)((const char*)Bs + cur * 8192 + rowb * 64 + ((q ^ ((rowb >> 1) & 3)) << 4));
        }
#pragma unroll
        for (int m = 0; m < 4; m++)
#pragma unroll
            for (int n = 0; n < 4; n++)
                acc[m][n] = __builtin_amdgcn_mfma_f32_16x16x32_bf16(bfr[n], af[m], acc[m][n], 0, 0, 0);
        __builtin_amdgcn_sched_barrier(0);
        __builtin_amdgcn_s_barrier();
        cur ^= 1;
    }

    float* outz = partial + (size_t)z * SEQ * DMODEL;
    int cl = lane & 15, g = lane >> 4;
#pragma unroll
    for (int m = 0; m < 4; m++) {
        int row = bm + wr + (m << 4) + cl;
#pragma unroll
        for (int n = 0; n < 4; n++) {
            int col0 = bn + wc + (n << 4) + (g << 2);
            *(f32x4*)&outz[(size_t)row * N + col0] = acc[m][n];
        }
    }
}

// ---------------- head GEMM: 256x128 tile, 8 waves, 2-buffer + vmcnt(3), fused no-max sum-exp ----------------
__global__ __launch_bounds__(512) void head_kernel(const short* __restrict__ A,
                                                   const short* __restrict__ Wt,
                                                   const float* __restrict__ bias,
                                                   float* __restrict__ out,
                                                   float* __restrict__ ps) {
    __shared__ short As[2][8192];
    __shared__ short Bs[2][4096];
    __shared__ float lsum[256][2];
    constexpr int K = DMODEL;
    int bid = blockIdx.x;
    int swz = (bid & 7) * 393 + (bid >> 3);
    int bm = (swz & 7) << 8;
    int bxp = swz >> 3;
    int bn = bxp << 7;
    int tid = threadIdx.x, lane = tid & 63, wid = tid >> 6;
    int wr = (wid >> 1) << 6;
    int wc = (wid & 1) << 6;
    f32x4 acc[4][4] = {};
    int rA = tid >> 2, sA = tid & 3;
    int q = lane >> 4, rr = lane & 15;

    auto STAGE = [&](int b, int k0) {
#pragma unroll
        for (int i = 0; i < 2; i++) {
            int r = rA + (i << 7);
            int gc = k0 + ((sA ^ ((r >> 1) & 3)) << 3);
            gload_lds16(A + (size_t)(bm + r) * K + gc, (char*)As + b * 16384 + (i << 13) + tid * 16);
        }
        {
            int gc = k0 + ((sA ^ ((rA >> 1) & 3)) << 3);
            gload_lds16(Wt + (size_t)(bn + rA) * K + gc, (char*)Bs + b * 8192 + tid * 16);
        }
    };

    STAGE(0, 0);
    int cur = 0;
    for (int k0 = 0; k0 < K; k0 += 32) {
        if (k0 + 32 < K) {
            STAGE(cur ^ 1, k0 + 32);
            asm volatile("s_waitcnt vmcnt(3)" ::: "memory");
        } else {
            asm volatile("s_waitcnt vmcnt(0)" ::: "memory");
        }
        __builtin_amdgcn_s_barrier();
        __builtin_amdgcn_sched_barrier(0);
        bf16x8 af[4], bfr[4];
#pragma unroll
        for (int m = 0; m < 4; m++) {
            int rowa = wr + (m << 4) + rr;
            af[m]  = *(const bf16x8*)((const char*)As + cur * 16384 + rowa * 64 + ((q ^ ((rowa >> 1) & 3)) << 4));
            int rowb = wc + (m << 4) + rr;
            bfr[m] = *(const bf16x8*)((const char*)Bs + cur * 8192 + rowb * 64 + ((q ^ ((rowb >> 1) & 3)) << 4));
        }
#pragma unroll
        for (int m = 0; m < 4; m++)
#pragma unroll
            for (int n = 0; n < 4; n++)
                acc[m][n] = __builtin_amdgcn_mfma_f32_16x16x32_bf16(bfr[n], af[m], acc[m][n], 0, 0, 0);
        __builtin_amdgcn_sched_barrier(0);
        __builtin_amdgcn_s_barrier();
        cur ^= 1;
    }

    int cl = lane & 15, g = lane >> 4;
#pragma unroll
    for (int m = 0; m < 4; m++) {
        int row = bm + wr + (m << 4) + cl;
        float s = 0.f;
#pragma unroll
        for (int n = 0; n < 4; n++) {
            int col0 = bn + wc + (n << 4) + (g << 2);
            f32x4 v = acc[m][n];
            if (col0 + 3 < NV) {
                float4 bv = *(const float4*)&bias[col0];
                v[0] += bv.x; v[1] += bv.y; v[2] += bv.z; v[3] += bv.w;
                *(f32x4*)&out[(size_t)row * NV + col0] = v;
                s += __expf(v[0]) + __expf(v[1]) + __expf(v[2]) + __expf(v[3]);
            } else {
#pragma unroll
                for (int j = 0; j < 4; j++) {
                    if (col0 + j < NV) {
                        float u = v[j] + bias[col0 + j];
                        out[(size_t)row * NV + col0 + j] = u;
                        s += __expf(u);
                    }
                }
            }
        }
        s += __shfl_xor(s, 16, 64);
        s += __shfl_xor(s, 32, 64);
        if (g == 0) lsum[wr + (m << 4) + cl][wid & 1] = s;
    }
    __syncthreads();
    if (tid < 256)
        ps[(size_t)(bm + tid) * NB + bxp] = lsum[tid][0] + lsum[tid][1];
}

// ---------------- LSE reduce + NLL: nll[row] = log(sum ps) - logit[row][target] ----------------
__global__ __launch_bounds__(256) void lsered_kernel(const float* __restrict__ ps,
                                                     const float* __restrict__ logits,
                                                     const int* __restrict__ targets,
                                                     float* __restrict__ nll) {
    int row = (blockIdx.x << 2) + (threadIdx.x >> 6);
    int lane = threadIdx.x & 63;
    const float* psr = ps + (size_t)row * NB;
    float s = 0.f;
    for (int j = lane; j < NB; j += 64) s += psr[j];
#pragma unroll
    for (int off = 32; off; off >>= 1) s += __shfl_xor(s, off, 64);
    if (lane == 0) nll[row] = logf(s) - logits[(size_t)row * NV + targets[row]];
}

// ---------------- MFMA flash attention: Q-tile 64, KV-tile 128, fixed-shift softmax ----------------
__global__ __launch_bounds__(256) void attn_kernel(const short* __restrict__ qkv,
                                                   bf16* __restrict__ o) {
    __shared__ short Ks[8192];
    __shared__ short Vt[8192];
    __shared__ short Ps[8192];
    int qt = gridDim.x - 1 - blockIdx.x;
    int h = blockIdx.y, tid = threadIdx.x;
    int lane = tid & 63, w = tid >> 6;
    int g = lane >> 4, c = lane & 15;
    int q0 = qt << 6;
    int nkt = (qt >> 1) + 1;

    bf16x8 qa[2];
    {
        const short* src = qkv + (size_t)(q0 + w * 16 + c) * 2304 + h * 64 + g * 8;
        qa[0] = *(const bf16x8*)src;
        qa[1] = *(const bf16x8*)(src + 32);
    }
    float l_i[4] = {};
    f32x4 oacc[4] = {};

    for (int kt = 0; kt < nkt; kt++) {
        bool last = (kt == nkt - 1);
        __syncthreads();
#pragma unroll
        for (int i = 0; i < 4; i++) {
            int r = (tid >> 3) + i * 32;
            int gslot = (tid & 7) ^ ((r & 7) ^ ((r >> 3) & 7));
            gload_lds16(qkv + (size_t)(kt * 128 + r) * 2304 + 768 + h * 64 + gslot * 8,
                        (char*)Ks + tid * 16 + i * 4096);
        }
#pragma unroll
        for (int ci = 0; ci < 4; ci++) {
            int rv = (tid >> 3) + ci * 32;
            bf16x8 vv = *(const bf16x8*)(qkv + (size_t)(kt * 128 + rv) * 2304 + 1536 + h * 64 + (tid & 7) * 8);
            int slot = rv >> 3;
#pragma unroll
            for (int j = 0; j < 8; j++) {
                int row = (tid & 7) * 8 + j;
                int sp = slot ^ ((row & 7) ^ ((row >> 3) & 7));
                Vt[row * 128 + sp * 8 + (rv & 7)] = vv[j];
            }
        }
        __syncthreads();

        f32x4 sacc[8] = {};
#pragma unroll
        for (int n = 0; n < 8; n++) {
#pragma unroll
            for (int ks = 0; ks < 2; ks++) {
                int row = n * 16 + c;
                int sp = (ks * 4 + g) ^ ((row & 7) ^ ((row >> 3) & 7));
                bf16x8 kf = *(const bf16x8*)(Ks + row * 64 + sp * 8);
                sacc[n] = __builtin_amdgcn_mfma_f32_16x16x32_bf16(qa[ks], kf, sacc[n], 0, 0, 0);
            }
        }
        if (!last) {
#pragma unroll
            for (int i = 0; i < 4; i++) {
                float rs = 0.f;
                int row = g * 4 + i;
                int sw = (row & 7) ^ (row >> 3);
#pragma unroll
                for (int n = 0; n < 8; n++) {
                    float p = __expf(sacc[n][i] * 0.125f);
                    rs += p;
                    int sp = (2 * n + (c >> 3)) ^ sw;
                    bf16 pb = __float2bfloat16(p);
                    Ps[w * 2048 + row * 128 + sp * 8 + (c & 7)] = *reinterpret_cast<short*>(&pb);
                }
                rs += __shfl_xor(rs, 1, 16);
                rs += __shfl_xor(rs, 2, 16);
                rs += __shfl_xor(rs, 4, 16);
                rs += __shfl_xor(rs, 8, 16);
                l_i[i] += rs;
            }
        } else {
#pragma unroll
            for (int i = 0; i < 4; i++) {
                float rs = 0.f;
                int qrow = q0 + w * 16 + g * 4 + i;
                int row = g * 4 + i;
                int sw = (row & 7) ^ (row >> 3);
#pragma unroll
                for (int n = 0; n < 8; n++) {
                    float p = __expf(sacc[n][i] * 0.125f);
                    if (kt * 128 + n * 16 + c > qrow) p = 0.f;
                    rs += p;
                    int sp = (2 * n + (c >> 3)) ^ sw;
                    bf16 pb = __float2bfloat16(p);
                    Ps[w * 2048 + row * 128 + sp * 8 + (c & 7)] = *reinterpret_cast<short*>(&pb);
                }
                rs += __shfl_xor(rs, 1, 16);
                rs += __shfl_xor(rs, 2, 16);
                rs += __shfl_xor(rs, 4, 16);
                rs += __shfl_xor(rs, 8, 16);
                l_i[i] += rs;
            }
        }
        bf16x8 pa[4];
#pragma unroll
        for (int ks = 0; ks < 4; ks++) {
            int sw = (c & 7) ^ (c >> 3);
            int sp = (ks * 4 + g) ^ sw;
            pa[ks] = *(const bf16x8*)(Ps + w * 2048 + c * 128 + sp * 8);
        }
#pragma unroll
        for (int n = 0; n < 4; n++) {
#pragma unroll
            for (int ks = 0; ks < 4; ks++) {
                int row = n * 16 + c;
                int sp = (ks * 4 + g) ^ ((row & 7) ^ ((row >> 3) & 7));
                bf16x8 vf = *(const bf16x8*)(Vt + row * 128 + sp * 8);
                oacc[n] = __builtin_amdgcn_mfma_f32_16x16x32_bf16(pa[ks], vf, oacc[n], 0, 0, 0);
            }
        }
    }
#pragma unroll
    for (int i = 0; i < 4; i++) {
        float inv = 1.0f / l_i[i];
#pragma unroll
        for (int n = 0; n < 4; n++)
            o[(size_t)(q0 + w * 16 + g * 4 + i) * DMODEL + h * 64 + n * 16 + c] =
                __float2bfloat16(oacc[n][i] * inv);
    }
}

// ---------------- loss = mean(nll) ----------------
__global__ __launch_bounds__(256) void loss_kernel(const float* __restrict__ nll,
                                                   float* __restrict__ out) {
    __shared__ float red[4];
    int tid = threadIdx.x;
    float acc = 0.f;
    for (int t = tid; t < SEQ; t += 256) acc += nll[t];
#pragma unroll
    for (int off = 32; off; off >>= 1) acc += __shfl_down(acc, off, 64);
    int wid = tid >> 6, lane = tid & 63;
    if (lane == 0) red[wid] = acc;
    __syncthreads();
    if (tid == 0) out[0] = (red[0] + red[1] + red[2] + red[3]) * (1.0f / SEQ);
}

extern "C" void kernel_launch(void* const* d_in, const int* in_sizes, int n_in,
                              void* d_out, int out_size, void* d_ws, size_t ws_size,
                              hipStream_t stream) {
    const int*   idx         = (const int*)d_in[0];
    const int*   targets     = (const int*)d_in[1];
    const float* wte         = (const float*)d_in[2];
    const float* wpe         = (const float*)d_in[3];
    const float* ln1_w       = (const float*)d_in[4];
    const float* ln1_b       = (const float*)d_in[5];
    const float* attn_w      = (const float*)d_in[6];
    const float* attn_b      = (const float*)d_in[7];
    const float* attn_proj_w = (const float*)d_in[8];
    const float* attn_proj_b = (const float*)d_in[9];
    const float* ln2_w       = (const float*)d_in[10];
    const float* ln2_b       = (const float*)d_in[11];
    const float* fc_w        = (const float*)d_in[12];
    const float* fc_b        = (const float*)d_in[13];
    const float* mlp_proj_w  = (const float*)d_in[14];
    const float* mlp_proj_b  = (const float*)d_in[15];
    const float* lnf_w       = (const float*)d_in[16];
    const float* lnf_b       = (const float*)d_in[17];
    const float* head_w      = (const float*)d_in[18];
    const float* head_b      = (const float*)d_in[19];

    float* logits = (float*)d_out;
    float* loss   = logits + (size_t)SEQ * NV;

    char* p = (char*)d_ws;
    float* x    = (float*)p;  p += (size_t)SEQ * DMODEL * 4;
    bf16*  h    = (bf16*)p;   p += (size_t)SEQ * DMODEL * 2;
    bf16*  o    = (bf16*)p;   p += (size_t)SEQ * DMODEL * 2;
    bf16*  qkvb = (bf16*)p;   p += (size_t)SEQ * 2304 * 2;
    bf16*  fcb  = (bf16*)p;   p += (size_t)SEQ * 3072 * 2;
    float* nll  = (float*)p;  p += (size_t)SEQ * 4;
    float* ps   = (float*)p;  p += (size_t)SEQ * NB * 4;
    bf16*  Wt   = (bf16*)p;

    bf16* wtA = Wt;
    bf16* wtP = wtA + (size_t)4 * 2304 * 768;
    bf16* wtF = wtP + (size_t)4 * 768 * 768;
    bf16* wtM = wtF + (size_t)4 * 3072 * 768;
    float* kscr = (float*)(wtM + (size_t)4 * 768 * 3072);

    embed_kernel<<<SEQ, 192, 0, stream>>>(idx, wte, wpe, x);

    transpb_kernel<<<dim3(2304 / 64, DMODEL / 64, 4), 256, 0, stream>>>(
        attn_w, wtA, DMODEL, 2304, (size_t)DMODEL * 2304, (size_t)2304 * DMODEL);
    transpb_kernel<<<dim3(DMODEL / 64, DMODEL / 64, 4), 256, 0, stream>>>(
        attn_proj_w, wtP, DMODEL, DMODEL, (size_t)DMODEL * DMODEL, (size_t)DMODEL * DMODEL);
    transpb_kernel<<<dim3(3072 / 64, DMODEL / 64, 4), 256, 0, stream>>>(
        fc_w, wtF, DMODEL, 3072, (size_t)DMODEL * 3072, (size_t)3072 * DMODEL);
    transpb_kernel<<<dim3(DMODEL / 64, 3072 / 64, 4), 256, 0, stream>>>(
        mlp_proj_w, wtM, 3072, DMODEL, (size_t)3072 * DMODEL, (size_t)DMODEL * 3072);

    ln_kernel<<<SEQ, 256, 0, stream>>>(x, ln1_w, ln1_b, h);
    for (int l = 0; l < NLAYER; l++) {
        mgemm_kernel<0, 0, 1><<<dim3((2304 / 128) * 16), 256, 0, stream>>>(
            (const short*)h, (const short*)(wtA + (size_t)l * 2304 * DMODEL),
            attn_b + l * 2304, nullptr, nullptr, qkvb, 2304, DMODEL);
        attn_kernel<<<dim3(SEQ / 64, NHEAD), 256, 0, stream>>>((const short*)qkvb, o);
        mgemmp_kernel<<<dim3((DMODEL / 128) * 16 * KSPLIT), 256, 0, stream>>>(
            (const short*)o, (const short*)(wtP + (size_t)l * DMODEL * DMODEL),
            kscr, DMODEL, DMODEL / KSPLIT, DMODEL);
        kredln_kernel<<<SEQ, 192, 0, stream>>>(
            kscr, attn_proj_b + l * DMODEL, x, ln2_w + l * DMODEL, ln2_b + l * DMODEL, h);
        mgemm_kernel<1, 0, 1><<<dim3((3072 / 128) * 16), 256, 0, stream>>>(
            (const short*)h, (const short*)(wtF + (size_t)l * 3072 * DMODEL),
            fc_b + l * 3072, nullptr, nullptr, fcb, 3072, DMODEL);
        mgemmp_kernel<<<dim3((DMODEL / 128) * 16 * KSPLIT), 256, 0, stream>>>(
            (const short*)fcb, (const short*)(wtM + (size_t)l * DMODEL * 3072),
            kscr, DMODEL, 3072 / KSPLIT, 3072);
        const float* nw = (l == NLAYER - 1) ? lnf_w : ln1_w + (l + 1) * DMODEL;
        const float* nb = (l == NLAYER - 1) ? lnf_b : ln1_b + (l + 1) * DMODEL;
        kredln_kernel<<<SEQ, 192, 0, stream>>>(
            kscr, mlp_proj_b + l * DMODEL, x, nw, nb, h);
    }

    transpb_kernel<<<dim3(NVPAD / 64, DMODEL / 64, 1), 256, 0, stream>>>(
        head_w, Wt, DMODEL, NV, 0, 0);
    head_kernel<<<dim3(8 * 393), 512, 0, stream>>>(
        (const short*)h, (const short*)Wt, head_b, logits, ps);
    lsered_kernel<<<SEQ / 4, 256, 0, stream>>>(ps, logits, targets, nll);
    loss_kernel<<<1, 256, 0, stream>>>(nll, loss);
}